// Round 2
// baseline (325.651 us; speedup 1.0000x reference)
//
#include <hip/hip_runtime.h>

// Problem constants (reference: B=4096, C=1000, T_THR=2, T_KD=20, ALPHA=0.8)
constexpr int   B        = 4096;
constexpr int   C        = 1000;
constexpr float ALPHA    = 0.8f;
constexpr float INV_TKD  = 0.05f;    // 1/20
constexpr float TKD2     = 400.0f;   // 20*20
constexpr float INV_TTHR = 0.5f;     // 1/2
constexpr float SENT     = -1e30f;   // finite sentinel for invalid lanes

// ---------------------------------------------------------------------------
// Kernel 1: one block (256 thr = 4 waves) per sample row; each thread owns 4
// consecutive floats (one float4; 250 of 256 threads valid). Streams the 8
// teachers with a register double-buffer so the next teacher's load is in
// flight during the current teacher's reduce chains. Cross-wave reductions:
// 6-step shuffle within wave + 4-slot LDS combine (2 barriers per branch).
// Emits per-row CE, G = sum_t thr_t*tgt_t*(KD_t - CE), rowmax over 8 teachers.
// ---------------------------------------------------------------------------
__global__ __launch_bounds__(256, 8) void row_kernel(
    const float* __restrict__ T0, const float* __restrict__ T1,
    const float* __restrict__ T2, const float* __restrict__ T3,
    const float* __restrict__ T4, const float* __restrict__ T5,
    const float* __restrict__ T6, const float* __restrict__ T7,
    const float* __restrict__ S,  const int* __restrict__ TGT,
    float* __restrict__ ws_ce, float* __restrict__ ws_g, float* __restrict__ ws_m)
{
    const int tid  = threadIdx.x;
    const int lane = tid & 63;
    const int wid  = tid >> 6;
    const int b    = blockIdx.x;                 // grid = B blocks
    const size_t base = (size_t)b * C;
    const bool valid = (tid < 250);              // thread owns floats [4*tid,4*tid+4)

    const int tgt  = TGT[b];                     // block-uniform
    const int oc4  = tgt >> 2;                   // owning thread
    const int slot = tgt & 3;                    // element within its float4

    // per-branch LDS slots (9 branches: 8 teachers + mimic) — distinct slots
    // per branch so no extra WAR barriers are needed.
    __shared__ float red1a[9][4], red1b[9][4];   // stage1: m1, m2 per wave
    __shared__ float red2a[9][4], red2b[9][4];   // stage2: Z, Ssum per wave
    __shared__ float tvs[9];                     // target logit per branch
    __shared__ float sredm[4], sred1[4], sredT[4];
    __shared__ float stv;                        // student target (shifted)

    auto load_row = [&](const float* __restrict__ p, float (&v)[4]) {
        if (valid) {
            float4 f = ((const float4*)(p + base))[tid];
            v[0] = f.x; v[1] = f.y; v[2] = f.z; v[3] = f.w;
        } else {
            v[0] = SENT; v[1] = SENT; v[2] = SENT; v[3] = SENT;
        }
    };

    auto wreduce_sum2 = [&](float& a, float& c) {
#pragma unroll
        for (int m = 1; m < 64; m <<= 1) {
            a += __shfl_xor(a, m, 64);
            c += __shfl_xor(c, m, 64);
        }
    };

    auto wreduce_top2 = [&](float& m1, float& m2) {
#pragma unroll
        for (int m = 1; m < 64; m <<= 1) {
            float o1 = __shfl_xor(m1, m, 64);
            float o2 = __shfl_xor(m2, m, 64);
            float n1 = fmaxf(m1, o1);
            float n2 = fmaxf(fminf(m1, o1), (m1 >= o1) ? m2 : o2);
            m1 = n1; m2 = n2;
        }
    };

    // ---------------- student pass (prefetch T0 behind it) ----------------
    float sv[4];
    load_row(S, sv);
    float v[4];
    load_row(T0, v);                              // in flight during student chains

    float smax = fmaxf(fmaxf(sv[0], sv[1]), fmaxf(sv[2], sv[3]));
#pragma unroll
    for (int m = 1; m < 64; m <<= 1) smax = fmaxf(smax, __shfl_xor(smax, m, 64));
    if (lane == 0) sredm[wid] = smax;
    __syncthreads();
    smax = fmaxf(fmaxf(sredm[0], sredm[1]), fmaxf(sredm[2], sredm[3]));

#pragma unroll
    for (int i = 0; i < 4; ++i) sv[i] -= smax;    // sv = s - max_s (finite sentinel lanes)

    float z1 = 0.0f, zT = 0.0f;
#pragma unroll
    for (int i = 0; i < 4; ++i) {
        z1 += __expf(sv[i]);
        zT += __expf(sv[i] * INV_TKD);
    }
    wreduce_sum2(z1, zT);
    if (lane == 0) { sred1[wid] = z1; sredT[wid] = zT; }
    if (tid == oc4) stv = sv[slot];
    __syncthreads();
    z1 = sred1[0] + sred1[1] + sred1[2] + sred1[3];
    zT = sredT[0] + sredT[1] + sredT[2] + sredT[3];
    const float logZ1 = __logf(z1);
    const float logZT = __logf(zT);
    const float ce = logZ1 - stv;                 // student cross-entropy

    // ---------------- teacher branches ----------------
    float acc[4] = {0.0f, 0.0f, 0.0f, 0.0f};
    float rowmax8 = SENT;
    float mx = 0.0f, s1 = 0.0f, s2 = 0.0f;        // online softmax over 9 teachers

    auto process = [&](const float (&w)[4], int br) -> float {
        // local top2 of 4
        float h1 = fmaxf(w[0], w[1]), l1 = fminf(w[0], w[1]);
        float h2 = fmaxf(w[2], w[3]), l2 = fminf(w[2], w[3]);
        float m1 = fmaxf(h1, h2);
        float m2 = fmaxf(fminf(h1, h2), (h1 >= h2) ? l1 : l2);
        wreduce_top2(m1, m2);
        if (lane == 0) { red1a[br][wid] = m1; red1b[br][wid] = m2; }
        if (tid == oc4) tvs[br] = w[slot];
        __syncthreads();
        m1 = red1a[br][0]; m2 = red1b[br][0];
#pragma unroll
        for (int k = 1; k < 4; ++k) {
            float a1 = red1a[br][k], a2 = red1b[br][k];
            float n1 = fmaxf(m1, a1);
            float n2 = fmaxf(fminf(m1, a1), (m1 >= a1) ? m2 : a2);
            m1 = n1; m2 = n2;
        }
        const float tval = tvs[br];

        float Z = 0.0f, Ss = 0.0f;
#pragma unroll
        for (int i = 0; i < 4; ++i) {
            float e = __expf((w[i] - m1) * INV_TKD);   // sentinel -> exp(-huge) = 0
            Z  += e;
            Ss += e * sv[i];
        }
        wreduce_sum2(Z, Ss);
        if (lane == 0) { red2a[br][wid] = Z; red2b[br][wid] = Ss; }
        __syncthreads();
        Z  = red2a[br][0] + red2a[br][1] + red2a[br][2] + red2a[br][3];
        Ss = red2b[br][0] + red2b[br][1] + red2b[br][2] + red2b[br][3];

        const float kd = TKD2 * (logZT - INV_TKD * (Ss / Z));
        const float margin = (tval == m1) ? (m1 - m2) : 0.0f;
        const float u = tval * (kd - ce);

        const float nmx = fmaxf(mx, margin);           // margins >= 0, mx init 0 safe
        const float sc  = __expf((mx - nmx) * INV_TTHR);
        const float ee  = __expf((margin - nmx) * INV_TTHR);
        s1 = s1 * sc + ee;
        s2 = s2 * sc + ee * u;
        mx = nmx;
        return m1;
    };

    const float* Tp[8] = {T0, T1, T2, T3, T4, T5, T6, T7};
    float vn[4];
#pragma unroll
    for (int t = 0; t < 8; ++t) {
        if (t < 7) load_row(Tp[t + 1], vn);       // next teacher's load in flight
#pragma unroll
        for (int i = 0; i < 4; ++i) acc[i] += v[i];
        rowmax8 = fmaxf(rowmax8, process(v, t));
        if (t < 7) {
#pragma unroll
            for (int i = 0; i < 4; ++i) v[i] = vn[i];
        }
    }

    // mimic = mean of the 8 teachers (9th branch; excluded from max_preds)
    float mv[4];
#pragma unroll
    for (int i = 0; i < 4; ++i) mv[i] = acc[i] * 0.125f;
    process(mv, 8);

    if (tid == 0) {
        ws_ce[b] = ce;
        ws_g[b]  = s2 / s1;
        ws_m[b]  = rowmax8;
    }
}

// ---------------------------------------------------------------------------
// Kernel 2: single block. max_preds over rows, then f64-accumulated mean of
// CE_b + (ALPHA/max_preds) * G_b.
// ---------------------------------------------------------------------------
__global__ __launch_bounds__(1024) void fin_kernel(
    const float* __restrict__ ce, const float* __restrict__ g,
    const float* __restrict__ m, float* __restrict__ out)
{
    __shared__ float  smax[1024];
    __shared__ double ssum[1024];
    const int tid = threadIdx.x;

    float mx = SENT;
    for (int i = tid; i < B; i += 1024) mx = fmaxf(mx, m[i]);
    smax[tid] = mx;
    __syncthreads();
    for (int s = 512; s > 0; s >>= 1) {
        if (tid < s) smax[tid] = fmaxf(smax[tid], smax[tid + s]);
        __syncthreads();
    }
    const float scale = ALPHA / smax[0];

    double acc = 0.0;
    for (int i = tid; i < B; i += 1024) acc += (double)(ce[i] + g[i] * scale);
    ssum[tid] = acc;
    __syncthreads();
    for (int s = 512; s > 0; s >>= 1) {
        if (tid < s) ssum[tid] += ssum[tid + s];
        __syncthreads();
    }
    if (tid == 0) out[0] = (float)(ssum[0] * (1.0 / (double)B));
}

extern "C" void kernel_launch(void* const* d_in, const int* in_sizes, int n_in,
                              void* d_out, int out_size, void* d_ws, size_t ws_size,
                              hipStream_t stream)
{
    const float* T0 = (const float*)d_in[0];
    const float* T1 = (const float*)d_in[1];
    const float* T2 = (const float*)d_in[2];
    const float* T3 = (const float*)d_in[3];
    const float* T4 = (const float*)d_in[4];
    const float* T5 = (const float*)d_in[5];
    const float* T6 = (const float*)d_in[6];
    const float* T7 = (const float*)d_in[7];
    const float* S  = (const float*)d_in[8];
    const int*   TG = (const int*)d_in[9];

    float* ws = (float*)d_ws;
    float* ws_ce = ws;
    float* ws_g  = ws + B;
    float* ws_m  = ws + 2 * B;

    row_kernel<<<B, 256, 0, stream>>>(T0, T1, T2, T3, T4, T5, T6, T7,
                                      S, TG, ws_ce, ws_g, ws_m);
    fin_kernel<<<1, 1024, 0, stream>>>(ws_ce, ws_g, ws_m, (float*)d_out);
}